// Round 10
// baseline (168.022 us; speedup 1.0000x reference)
//
#include <hip/hip_runtime.h>

#define NCELLS 1024
#define LDIM   30
#define GDIM   10000
#define NBATCH 64
#define GPB    256     // genes per tile (4 waves x 64)
#define WGENES 64      // genes per wave per tile
#define WCAP   64      // per-wave cell list cap (binomial(1024,1/64): mean 16, +12 sigma)
#define TPB    2       // tiles per block (pipelined)
#define NTILES 40      // ceil(GDIM/GPB)
#define NCHUNK (NTILES / TPB)   // 20 -> grid 64 x 20 = 1280 blocks = 5/CU exact

typedef unsigned int u32;
typedef unsigned long long u64;

#define GLOBAL_AS __attribute__((address_space(1)))
#define LDS_AS    __attribute__((address_space(3)))

// grid = (NBATCH, NCHUNK) = 1280 persistent blocks (5/CU, LDS 31.7KB x 5).
//
// R9 residuals fixed here:
//  (a) W/Bb/px for tile t+1 prefetched into REGISTERS right after the t+1
//      DMA issue -> they fly over tile t's cell loop; the t+1 vmcnt(0) drain
//      no longer exposes W's L2/L3 latency at every tile boundary.
//  (b) cell loop: next group's ids/sf readlane'd ONE GROUP AHEAD (R1's
//      proven pattern) so the compiler can issue the next 4 z-row s_loads
//      under the current group's FMAs instead of restarting the dependent
//      readlane->s_load chain cold 4x per tile.
// All validated patterns kept: wave-private DMA chunks at full-wave exec
// with branchless OOB clamp (fires only for gene rows >= GDIM, never read),
// wave-local vmcnt(0)+sched_barrier drains (no __syncthreads), ballot
// prefix-compaction scan, readlane sources pinned under full exec, NO
// divergent early return, stores predicated on `valid`.
__global__ __launch_bounds__(256, 5) void decoder_kernel(
    const float* __restrict__ z,      // [N,L]     f32
    const void*  __restrict__ cand1,  // [N]  bcov or sf (classified on device)
    const void*  __restrict__ cand2,  // [N]  the other one
    const float* __restrict__ W,      // [L,G]     f32
    const float* __restrict__ A,      // [NB,G,L]  f32
    const float* __restrict__ Bb,     // [NB,G]    f32
    const float* __restrict__ px,     // [G]       f32
    float* __restrict__ out)          // [N*G + G] f32
{
    const int b    = blockIdx.x;
    const int tid  = threadIdx.x;
    const int lane = tid & 63;
    const int wid  = __builtin_amdgcn_readfirstlane(tid >> 6);  // 0..3 uniform

    __shared__ __align__(16) float a_sh[GPB * LDIM];  // 30720 B (single buffer)
    __shared__ int wlist[4][WCAP];                    //  1024 B -> 31744 total

    float* const wsh = a_sh + wid * (WGENES * LDIM);  // wave-private 7.5 KB
    const size_t atot = (size_t)NBATCH * GDIM * LDIM;

    // full-wave-exec DMA of one wave-chunk (64 genes x 30 f32 = 7680 B):
    // 7x16B rounds + 2x4B rounds; LDS dest wave-uniform, HW adds lane*width.
    auto stage = [&](int tile) {
        const int gwave = tile * GPB + wid * WGENES;
        const size_t abase = ((size_t)b * GDIM + gwave) * LDIM;
        #pragma unroll
        for (int k = 0; k < 7; k++) {
            size_t gidx = abase + (size_t)(k * 64 + lane) * 4;
            if (gidx + 4 > atot) gidx = atot - 4;   // only fires for gene>=GDIM
            __builtin_amdgcn_global_load_lds(
                (const GLOBAL_AS void*)(A + gidx),
                (LDS_AS void*)(wsh + k * 256), 16, 0, 0);
        }
        #pragma unroll
        for (int j = 0; j < 2; j++) {
            size_t fidx = abase + (size_t)(7 * 256 + j * 64 + lane);
            if (fidx + 1 > atot) fidx = atot - 1;   // only fires for gene>=GDIM
            __builtin_amdgcn_global_load_lds(
                (const GLOBAL_AS void*)(A + fidx),
                (LDS_AS void*)(wsh + 7 * 256 + j * 64), 4, 0, 0);
        }
    };

    // W row / bias / px prefetch into registers (coalesced vector loads)
    auto prefetchW = [&](int tile, float* wreg, float& h3r, float& pxr) {
        const int g = tile * GPB + wid * WGENES + lane;
        const int gc = g < GDIM ? g : GDIM - 1;
        #pragma unroll
        for (int l = 0; l < LDIM; l++) wreg[l] = W[(size_t)l * GDIM + gc];
        h3r = Bb[(size_t)b * GDIM + gc];
        pxr = px[gc];
    };

    const int tile0 = blockIdx.y * TPB;                 // 0..38, step 2
    stage(tile0);                                       // prologue DMA, tile 0

    // ---- classify the two 1024-elem inputs (one load + ballot) ----
    // int32 0..63 words all < 64u; uniform-[0,1) f32 bit patterns are not.
    const u32 probe = ((const u32*)cand1)[lane];
    const bool c1_is_int = __all(probe < 64u);
    const int*   bcov = c1_is_int ? (const int*)cand1   : (const int*)cand2;
    const float* sf   = c1_is_int ? (const float*)cand2 : (const float*)cand1;

    // tile0's W bundle flies with the prologue DMA
    float wcur[LDIM], wnext[LDIM];
    float h3cur, pxcur, h3next, pxnext;
    prefetchW(tile0, wcur, h3cur, pxcur);

    // ---- wave-private cell scan (overlaps DMA): int4 loads + ballot ----
    wlist[wid][lane] = 0;                       // garbage-safe default id
    int cnt = 0;                                // wave-uniform running count
    const u64 below = (1ull << lane) - 1ull;
    const int4* b4 = (const int4*)bcov;         // input buffers 16B-aligned
    #pragma unroll
    for (int i0 = 0; i0 < 4; i0++) {
        const int4 v = b4[i0 * 64 + lane];      // coalesced 1KB
        const int base = i0 * 256 + lane * 4;
        #pragma unroll
        for (int j = 0; j < 4; j++) {
            const int vj = (j == 0) ? v.x : (j == 1) ? v.y : (j == 2) ? v.z : v.w;
            const u64 mb = __ballot(vj == b);
            if (vj == b) {
                const int pos = cnt + (int)__popcll(mb & below);
                if (pos < WCAP) wlist[wid][pos] = base + j;
            }
            cnt += (int)__popcll(mb);
        }
    }
    const int total = cnt < WCAP ? cnt : WCAP;

    // cell ids + size factors into registers under FULL exec, pinned so the
    // compiler can neither sink nor predicate them (v_readlane reads any lane).
    int   myid = wlist[wid][lane];              // same-wave ds ops, lgkm-ordered
    float mysf = sf[myid];                      // gather, ids in [0,1024)
    asm volatile("" : "+v"(myid), "+v"(mysf));  // materialize HERE, full exec

    auto tile_body = [&](int tile, const float* wreg, float h3, float pxv,
                         bool pf_next) {
        const int g = tile * GPB + wid * WGENES + lane;
        const bool valid = (g < GDIM);

        // ---- wave-local drain of this wave's DMA (NOT a barrier) ----
        asm volatile("s_waitcnt vmcnt(0)" ::: "memory");
        __builtin_amdgcn_sched_barrier(0);   // rule #18: nothing hoists past wait

        // fused row: m[l] = wreg[l] + wsh[lane][l]; 120B rows -> ds_read_b64,
        // bank stride 30 -> 2-way aliasing only (free on CDNA4)
        float m[LDIM];
        {
            const float2* ar = (const float2*)(wsh + lane * LDIM);
            #pragma unroll
            for (int j = 0; j < LDIM / 2; j++) {
                const float2 w2 = ar[j];
                m[2 * j]     = wreg[2 * j]     + w2.x;
                m[2 * j + 1] = wreg[2 * j + 1] + w2.y;
            }
        }

        // tile-t LDS reads must retire before DMA t+1 overwrites the buffer
        asm volatile("s_waitcnt lgkmcnt(0)" ::: "memory");
        __builtin_amdgcn_sched_barrier(0);
        if (pf_next) {
            stage(tile + 1);                       // DMA flies over cell loop
            prefetchW(tile + 1, wnext, h3next, pxnext);  // W bundle too
        }

        // second output: inverse_dispersion = exp(px_r), f32 at offset N*G
        if (valid && b == 0) out[(size_t)NCELLS * GDIM + g] = __expf(pxv);

        // ---- cell loop: 4-cell groups, ids/sf prefetched ONE group ahead --
        int nid0 = __builtin_amdgcn_readlane(myid, 0);
        int nid1 = __builtin_amdgcn_readlane(myid, 1);
        int nid2 = __builtin_amdgcn_readlane(myid, 2);
        int nid3 = __builtin_amdgcn_readlane(myid, 3);
        float nsf0 = __int_as_float(__builtin_amdgcn_readlane(__float_as_int(mysf), 0));
        float nsf1 = __int_as_float(__builtin_amdgcn_readlane(__float_as_int(mysf), 1));
        float nsf2 = __int_as_float(__builtin_amdgcn_readlane(__float_as_int(mysf), 2));
        float nsf3 = __int_as_float(__builtin_amdgcn_readlane(__float_as_int(mysf), 3));
        int c = 0;
        for (; c + 4 <= total; c += 4) {
            const int cell0 = nid0, cell1 = nid1, cell2 = nid2, cell3 = nid3;
            const float s0 = nsf0, s1 = nsf1, s2 = nsf2, s3 = nsf3;
            const int n = c + 4;           // prefetch next group (&63: in-range
            nid0 = __builtin_amdgcn_readlane(myid, n & 63);        // reg, maybe
            nid1 = __builtin_amdgcn_readlane(myid, (n + 1) & 63);  // unused)
            nid2 = __builtin_amdgcn_readlane(myid, (n + 2) & 63);
            nid3 = __builtin_amdgcn_readlane(myid, (n + 3) & 63);
            nsf0 = __int_as_float(__builtin_amdgcn_readlane(__float_as_int(mysf), n & 63));
            nsf1 = __int_as_float(__builtin_amdgcn_readlane(__float_as_int(mysf), (n + 1) & 63));
            nsf2 = __int_as_float(__builtin_amdgcn_readlane(__float_as_int(mysf), (n + 2) & 63));
            nsf3 = __int_as_float(__builtin_amdgcn_readlane(__float_as_int(mysf), (n + 3) & 63));
            const float* z0 = z + (size_t)cell0 * LDIM;   // uniform -> s_load
            const float* z1 = z + (size_t)cell1 * LDIM;
            const float* z2 = z + (size_t)cell2 * LDIM;
            const float* z3 = z + (size_t)cell3 * LDIM;
            float a0 = h3, b0 = 0.f, a1 = h3, b1 = 0.f;
            float a2 = h3, b2 = 0.f, a3 = h3, b3 = 0.f;
            #pragma unroll
            for (int l = 0; l < LDIM; l += 2) {
                a0 = fmaf(m[l],     z0[l],     a0);
                b0 = fmaf(m[l + 1], z0[l + 1], b0);
                a1 = fmaf(m[l],     z1[l],     a1);
                b1 = fmaf(m[l + 1], z1[l + 1], b1);
                a2 = fmaf(m[l],     z2[l],     a2);
                b2 = fmaf(m[l + 1], z2[l + 1], b2);
                a3 = fmaf(m[l],     z3[l],     a3);
                b3 = fmaf(m[l + 1], z3[l + 1], b3);
            }
            float x0 = a0 + b0, x1 = a1 + b1, x2 = a2 + b2, x3 = a3 + b3;
            // stable softplus: max(x,0) + log(1 + exp(-|x|))
            float p0 = fmaxf(x0, 0.f) + __logf(1.f + __expf(-fabsf(x0)));
            float p1 = fmaxf(x1, 0.f) + __logf(1.f + __expf(-fabsf(x1)));
            float p2 = fmaxf(x2, 0.f) + __logf(1.f + __expf(-fabsf(x2)));
            float p3 = fmaxf(x3, 0.f) + __logf(1.f + __expf(-fabsf(x3)));
            if (valid) {
                __builtin_nontemporal_store(p0 * s0, &out[(size_t)cell0 * GDIM + g]);
                __builtin_nontemporal_store(p1 * s1, &out[(size_t)cell1 * GDIM + g]);
                __builtin_nontemporal_store(p2 * s2, &out[(size_t)cell2 * GDIM + g]);
                __builtin_nontemporal_store(p3 * s3, &out[(size_t)cell3 * GDIM + g]);
            }
        }
        for (; c < total; c++) {              // 0..3 tail cells
            const int cell0 = __builtin_amdgcn_readlane(myid, c);
            const float s0 = __int_as_float(__builtin_amdgcn_readlane(__float_as_int(mysf), c));
            const float* z0 = z + (size_t)cell0 * LDIM;
            float a0 = h3, b0 = 0.f;
            #pragma unroll
            for (int l = 0; l < LDIM; l += 2) {
                a0 = fmaf(m[l],     z0[l],     a0);
                b0 = fmaf(m[l + 1], z0[l + 1], b0);
            }
            float x0 = a0 + b0;
            float p0 = fmaxf(x0, 0.f) + __logf(1.f + __expf(-fabsf(x0)));
            if (valid)
                __builtin_nontemporal_store(p0 * s0, &out[(size_t)cell0 * GDIM + g]);
        }
    };

    tile_body(tile0,     wcur,  h3cur,  pxcur,  true);
    tile_body(tile0 + 1, wnext, h3next, pxnext, false);
}

extern "C" void kernel_launch(void* const* d_in, const int* in_sizes, int n_in,
                              void* d_out, int out_size, void* d_ws, size_t ws_size,
                              hipStream_t stream) {
    // Bind inputs by element count (robust to ordering); the two 1024-element
    // inputs (bcov / size_factor) are disambiguated on device by content.
    const float* z  = nullptr;   // 30720
    const float* W  = nullptr;   // 300000
    const float* A  = nullptr;   // 19200000
    const float* Bb = nullptr;   // 640000
    const float* px = nullptr;   // 10000
    const void*  p1024[2] = {nullptr, nullptr};
    int n1024 = 0;
    for (int i = 0; i < n_in; i++) {
        switch (in_sizes[i]) {
            case NCELLS * LDIM:        z  = (const float*)d_in[i]; break;
            case LDIM * GDIM:          W  = (const float*)d_in[i]; break;
            case NBATCH * GDIM * LDIM: A  = (const float*)d_in[i]; break;
            case NBATCH * GDIM:        Bb = (const float*)d_in[i]; break;
            case GDIM:                 px = (const float*)d_in[i]; break;
            case NCELLS:
                if (n1024 < 2) p1024[n1024] = d_in[i];
                n1024++;
                break;
            default: break;
        }
    }
    if (!z || !W || !A || !Bb || !px || n1024 != 2) {  // fallback: dict order
        z  = (const float*)d_in[0];
        p1024[0] = d_in[1];
        p1024[1] = d_in[2];
        W  = (const float*)d_in[3];
        A  = (const float*)d_in[4];
        Bb = (const float*)d_in[5];
        px = (const float*)d_in[6];
    }
    float* out = (float*)d_out;

    decoder_kernel<<<dim3(NBATCH, NCHUNK), 256, 0, stream>>>(
        z, p1024[0], p1024[1], W, A, Bb, px, out);
}